// Round 8
// baseline (181.598 us; speedup 1.0000x reference)
//
#include <hip/hip_runtime.h>

#define NNODES 196608
#define NH 9
#define F 64
#define K_TOT 576      // NH * F
#define LN_EPS 1e-5f

typedef __attribute__((ext_vector_type(8))) short short8v;
typedef __attribute__((ext_vector_type(4))) float f32x4;

__device__ __forceinline__ unsigned short f2bf(float f) {
    unsigned int u = __float_as_uint(f);
    u += 0x7fff + ((u >> 16) & 1);          // round-to-nearest-even
    return (unsigned short)(u >> 16);
}
__device__ __forceinline__ float silu_f(float z) { return z / (1.0f + __expf(-z)); }

// Build bf16 transposed weights Wt[o][k] (k = head*64 + f) from f32 W[head][f][o].
__global__ __launch_bounds__(256) void prep_wt(const float* __restrict__ W1,
                                               const float* __restrict__ W2,
                                               unsigned short* __restrict__ Wt1,
                                               unsigned short* __restrict__ Wt2) {
    int tid = blockIdx.x * 256 + threadIdx.x;
    if (tid >= F * K_TOT) return;
    int k = tid % K_TOT, o = tid / K_TOT;
    Wt1[tid] = f2bf(W1[(size_t)k * F + o]);
    Wt2[tid] = f2bf(W2[(size_t)k * F + o]);
}

// LN + SiLU, f32 in -> bf16 out. 16 threads per row, float4 per thread.
__global__ __launch_bounds__(256) void ln1_silu(const float* __restrict__ x,
                                                const float* __restrict__ w,
                                                const float* __restrict__ b,
                                                unsigned short* __restrict__ out) {
    const int t = threadIdx.x;
    const int row = blockIdx.x * 16 + (t >> 4);
    const int fl = (t & 15) * 4;
    const float4 v = *(const float4*)(x + (size_t)row * F + fl);
    float s = v.x + v.y + v.z + v.w;
    float ss = v.x * v.x + v.y * v.y + v.z * v.z + v.w * v.w;
#pragma unroll
    for (int o = 8; o; o >>= 1) { s += __shfl_xor(s, o); ss += __shfl_xor(ss, o); }
    const float mu = s * (1.0f / F);
    const float rstd = rsqrtf(ss * (1.0f / F) - mu * mu + LN_EPS);
    const float4 wv = *(const float4*)(w + fl);
    const float4 bv = *(const float4*)(b + fl);
    ushort4 o4;
    o4.x = f2bf(silu_f((v.x - mu) * rstd * wv.x + bv.x));
    o4.y = f2bf(silu_f((v.y - mu) * rstd * wv.y + bv.y));
    o4.z = f2bf(silu_f((v.z - mu) * rstd * wv.z + bv.z));
    o4.w = f2bf(silu_f((v.w - mu) * rstd * wv.w + bv.w));
    *(ushort4*)(out + (size_t)row * F + fl) = o4;
}

// BARRIER-FREE gconv (round-8 restructure). Wave owns 32 nodes (2 m-tiles) and
// computes all 64 outputs for them: no cross-wave data sharing -> no s_barrier,
// no LDS. A-fragments gathered per-lane straight from global bf16 h (lane(l16,lg)
// reads row idx[l16], 16B at k=kh*32+lg*8 == the exact 16x16x32 A layout).
// B-fragments read per k-step from L2-resident Wt (144KB, hot in all XCD L2s).
// Round-7 lesson: the per-head barrier convoy (phase = max of 8 random-gather
// latencies) was the binder, not HBM latency (45KB/CU in flight >> 7KB needed).
// A double-buffered 2 heads deep; LN2 epilogue in-register (16-lane shuffles).
template<int FINAL>
__global__ __launch_bounds__(256) __attribute__((amdgpu_waves_per_eu(3, 3)))
void gconv_mfma(
    const unsigned short* __restrict__ h,
    const int* __restrict__ adjc,
    const unsigned short* __restrict__ Wt,
    const float* __restrict__ bias,
    const float* __restrict__ lnw, const float* __restrict__ lnb,
    const float* __restrict__ xres,
    void* __restrict__ outv)
{
    const int wave = threadIdx.x >> 6;
    const int lane = threadIdx.x & 63;
    const int l16 = lane & 15, lg = lane >> 4;
    const int nodeBase = blockIdx.x * 128 + wave * 32;

    // Lane's two A-rows: nodes nodeBase+l16 (m=0) and nodeBase+16+l16 (m=1).
    int idx0[NH], idx1[NH];
    {
        const int* a0 = adjc + (size_t)(nodeBase + l16) * NH;
        const int* a1 = adjc + (size_t)(nodeBase + 16 + l16) * NH;
#pragma unroll
        for (int hh = 0; hh < NH; ++hh) { idx0[hh] = a0[hh]; idx1[hh] = a1[hh]; }
    }

    // B base for this lane: o = ot*16 + l16 (ot adds 16*K_TOT), k-chunk lg*8.
    const unsigned short* bp = Wt + (size_t)l16 * K_TOT + lg * 8;

    f32x4 acc[2][4];                       // [m][ot]
#pragma unroll
    for (int m = 0; m < 2; ++m)
#pragma unroll
        for (int ot = 0; ot < 4; ++ot) acc[m][ot] = (f32x4){0.f, 0.f, 0.f, 0.f};

    short8v Ax[2][2][2];                   // [pipe][m][kh] — static indices only

#define ALOAD(P, HH) do {                                                       \
        const unsigned short* r0 = h + (size_t)idx0[HH] * F + lg * 8;           \
        const unsigned short* r1 = h + (size_t)idx1[HH] * F + lg * 8;           \
        Ax[P][0][0] = *(const short8v*)(r0);                                    \
        Ax[P][0][1] = *(const short8v*)(r0 + 32);                               \
        Ax[P][1][0] = *(const short8v*)(r1);                                    \
        Ax[P][1][1] = *(const short8v*)(r1 + 32);                               \
    } while (0)

#define HSTEP(P, HH)                                                            \
    _Pragma("unroll")                                                           \
    for (int kh = 0; kh < 2; ++kh) {                                            \
        const short8v bf0 = *(const short8v*)(bp + 0 * 16 * K_TOT + ((HH) * 2 + kh) * 32); \
        const short8v bf1 = *(const short8v*)(bp + 1 * 16 * K_TOT + ((HH) * 2 + kh) * 32); \
        const short8v bf2 = *(const short8v*)(bp + 2 * 16 * K_TOT + ((HH) * 2 + kh) * 32); \
        const short8v bf3 = *(const short8v*)(bp + 3 * 16 * K_TOT + ((HH) * 2 + kh) * 32); \
        acc[0][0] = __builtin_amdgcn_mfma_f32_16x16x32_bf16(Ax[P][0][kh], bf0, acc[0][0], 0, 0, 0); \
        acc[0][1] = __builtin_amdgcn_mfma_f32_16x16x32_bf16(Ax[P][0][kh], bf1, acc[0][1], 0, 0, 0); \
        acc[0][2] = __builtin_amdgcn_mfma_f32_16x16x32_bf16(Ax[P][0][kh], bf2, acc[0][2], 0, 0, 0); \
        acc[0][3] = __builtin_amdgcn_mfma_f32_16x16x32_bf16(Ax[P][0][kh], bf3, acc[0][3], 0, 0, 0); \
        acc[1][0] = __builtin_amdgcn_mfma_f32_16x16x32_bf16(Ax[P][1][kh], bf0, acc[1][0], 0, 0, 0); \
        acc[1][1] = __builtin_amdgcn_mfma_f32_16x16x32_bf16(Ax[P][1][kh], bf1, acc[1][1], 0, 0, 0); \
        acc[1][2] = __builtin_amdgcn_mfma_f32_16x16x32_bf16(Ax[P][1][kh], bf2, acc[1][2], 0, 0, 0); \
        acc[1][3] = __builtin_amdgcn_mfma_f32_16x16x32_bf16(Ax[P][1][kh], bf3, acc[1][3], 0, 0, 0); \
    }

    ALOAD(0, 0);
    ALOAD(1, 1);
#pragma unroll
    for (int hh = 0; hh < NH; ++hh) {
        HSTEP(hh & 1, hh);
        if (hh + 2 < NH) ALOAD(hh & 1, hh + 2);   // refill consumed slot, 2-deep pipe
    }
#undef ALOAD
#undef HSTEP

    // Epilogue, fully in-register. D layout: col(o)=ot*16+l16, row=lg*4+r ->
    // node = nodeBase + m*16 + lg*4 + r. Each node's 64 outputs live on the 16
    // lanes sharing lg (l16=0..15) x 4 ot regs -> shuffle-reduce masks 1,2,4,8.
    float vbias[4];
#pragma unroll
    for (int ot = 0; ot < 4; ++ot) vbias[ot] = bias[ot * 16 + l16];

    if (FINAL) {
        float* out = (float*)outv;
#pragma unroll
        for (int m = 0; m < 2; ++m)
#pragma unroll
            for (int r = 0; r < 4; ++r) {
                const int node = nodeBase + m * 16 + lg * 4 + r;
#pragma unroll
                for (int ot = 0; ot < 4; ++ot) {
                    const int o = ot * 16 + l16;
                    out[(size_t)node * F + o] =
                        acc[m][ot][r] + vbias[ot] + xres[(size_t)node * F + o];
                }
            }
    } else {
        float lw[4], lb[4];
#pragma unroll
        for (int ot = 0; ot < 4; ++ot) { lw[ot] = lnw[ot * 16 + l16]; lb[ot] = lnb[ot * 16 + l16]; }
        unsigned short* out = (unsigned short*)outv;
#pragma unroll
        for (int m = 0; m < 2; ++m)
#pragma unroll
            for (int r = 0; r < 4; ++r) {
                const float v0 = acc[m][0][r] + vbias[0];
                const float v1 = acc[m][1][r] + vbias[1];
                const float v2 = acc[m][2][r] + vbias[2];
                const float v3 = acc[m][3][r] + vbias[3];
                float s  = v0 + v1 + v2 + v3;
                float ss = v0 * v0 + v1 * v1 + v2 * v2 + v3 * v3;
                s += __shfl_xor(s, 1); ss += __shfl_xor(ss, 1);
                s += __shfl_xor(s, 2); ss += __shfl_xor(ss, 2);
                s += __shfl_xor(s, 4); ss += __shfl_xor(ss, 4);
                s += __shfl_xor(s, 8); ss += __shfl_xor(ss, 8);
                const float mu = s * (1.0f / F);
                const float rstd = rsqrtf(ss * (1.0f / F) - mu * mu + LN_EPS);
                const int node = nodeBase + m * 16 + lg * 4 + r;
                out[(size_t)node * F +  0 + l16] = f2bf(silu_f((v0 - mu) * rstd * lw[0] + lb[0]));
                out[(size_t)node * F + 16 + l16] = f2bf(silu_f((v1 - mu) * rstd * lw[1] + lb[1]));
                out[(size_t)node * F + 32 + l16] = f2bf(silu_f((v2 - mu) * rstd * lw[2] + lb[2]));
                out[(size_t)node * F + 48 + l16] = f2bf(silu_f((v3 - mu) * rstd * lw[3] + lb[3]));
            }
    }
}

extern "C" void kernel_launch(void* const* d_in, const int* in_sizes, int n_in,
                              void* d_out, int out_size, void* d_ws, size_t ws_size,
                              hipStream_t stream)
{
    const float* x    = (const float*)d_in[0];
    const int*   adjc = (const int*)d_in[1];
    const float* ln1w = (const float*)d_in[2];
    const float* ln1b = (const float*)d_in[3];
    const float* W1   = (const float*)d_in[4];
    const float* b1   = (const float*)d_in[5];
    const float* ln2w = (const float*)d_in[6];
    const float* ln2b = (const float*)d_in[7];
    const float* W2   = (const float*)d_in[8];
    const float* b2   = (const float*)d_in[9];
    float* out = (float*)d_out;

    unsigned short* h1  = (unsigned short*)d_ws;              // 25.2 MB bf16
    unsigned short* h2  = h1 + (size_t)NNODES * F;            // 25.2 MB bf16
    unsigned short* Wt1 = h2 + (size_t)NNODES * F;            // 144 KB
    unsigned short* Wt2 = Wt1 + F * K_TOT;                    // 144 KB

    prep_wt<<<(F * K_TOT + 255) / 256, 256, 0, stream>>>(W1, W2, Wt1, Wt2);
    ln1_silu<<<NNODES / 16, 256, 0, stream>>>(x, ln1w, ln1b, h1);
    gconv_mfma<0><<<NNODES / 128, 256, 0, stream>>>(h1, adjc, Wt1, b1, ln2w, ln2b, nullptr, h2);
    gconv_mfma<1><<<NNODES / 128, 256, 0, stream>>>(h2, adjc, Wt2, b2, nullptr, nullptr, x, out);
}

// Round 9
// 123.111 us; speedup vs baseline: 1.4751x; 1.4751x over previous
//
#include <hip/hip_runtime.h>

#define NNODES 196608
#define NH 9
#define F 64
#define K_TOT 576      // NH * F
#define KSTEPS 18      // K_TOT / 32
#define LN_EPS 1e-5f

typedef __attribute__((ext_vector_type(8))) short short8v;
typedef __attribute__((ext_vector_type(4))) float f32x4;

__device__ __forceinline__ unsigned short f2bf(float f) {
    unsigned int u = __float_as_uint(f);
    u += 0x7fff + ((u >> 16) & 1);          // round-to-nearest-even
    return (unsigned short)(u >> 16);
}
__device__ __forceinline__ float silu_f(float z) { return z / (1.0f + __expf(-z)); }

// Async global->LDS, 16 B per lane. Dest is wave-uniform base + lane*16 (linear).
__device__ __forceinline__ void gload_lds16(const void* g, void* l) {
    __builtin_amdgcn_global_load_lds((__attribute__((address_space(1))) void*)g,
                                     (__attribute__((address_space(3))) void*)l,
                                     16, 0, 0);
}

// Build bf16 transposed weights Wt[o][k] (k = head*64 + f) from f32 W[head][f][o].
__global__ __launch_bounds__(256) void prep_wt(const float* __restrict__ W1,
                                               const float* __restrict__ W2,
                                               unsigned short* __restrict__ Wt1,
                                               unsigned short* __restrict__ Wt2) {
    int tid = blockIdx.x * 256 + threadIdx.x;
    if (tid >= F * K_TOT) return;
    int k = tid % K_TOT, o = tid / K_TOT;
    Wt1[tid] = f2bf(W1[(size_t)k * F + o]);
    Wt2[tid] = f2bf(W2[(size_t)k * F + o]);
}

// LN + SiLU, f32 in -> bf16 out. 16 threads per row, float4 per thread.
__global__ __launch_bounds__(256) void ln1_silu(const float* __restrict__ x,
                                                const float* __restrict__ w,
                                                const float* __restrict__ b,
                                                unsigned short* __restrict__ out) {
    const int t = threadIdx.x;
    const int row = blockIdx.x * 16 + (t >> 4);
    const int fl = (t & 15) * 4;
    const float4 v = *(const float4*)(x + (size_t)row * F + fl);
    float s = v.x + v.y + v.z + v.w;
    float ss = v.x * v.x + v.y * v.y + v.z * v.z + v.w * v.w;
#pragma unroll
    for (int o = 8; o; o >>= 1) { s += __shfl_xor(s, o); ss += __shfl_xor(ss, o); }
    const float mu = s * (1.0f / F);
    const float rstd = rsqrtf(ss * (1.0f / F) - mu * mu + LN_EPS);
    const float4 wv = *(const float4*)(w + fl);
    const float4 bv = *(const float4*)(b + fl);
    ushort4 o4;
    o4.x = f2bf(silu_f((v.x - mu) * rstd * wv.x + bv.x));
    o4.y = f2bf(silu_f((v.y - mu) * rstd * wv.y + bv.y));
    o4.z = f2bf(silu_f((v.z - mu) * rstd * wv.z + bv.z));
    o4.w = f2bf(silu_f((v.w - mu) * rstd * wv.w + bv.w));
    *(ushort4*)(out + (size_t)row * F + fl) = o4;
}

// Block = 64 nodes, 4 waves; gathered rows staged ONCE per block via global_load_lds,
// XOR-swizzled on both the global source and the ds_read address (rule #21).
// Triple-buffered LDS + counted vmcnt(2) (T4): stage(h+1),(h+2) stay in flight
// across the barrier — depth-2 prefetch (round 7, 56.4 us/gconv).
// Round-8 lesson: barrier-free per-wave ownership REGRESSED (86 us) — fewer waves
// + B-loads on the MFMA critical path; block-level concurrency is the lever.
// Round-9 change: DROP amdgpu_waves_per_eu(3,4) — it capped residency at ~3
// blocks/CU while VGPR(64)/LDS(24.6KB) allow 6. Codegen needs no pin (bfrag
// re-loads from hot L2 at VGPR 64 anyway).
template<int FINAL>
__global__ __launch_bounds__(256)
void gconv_mfma(
    const unsigned short* __restrict__ h,
    const int* __restrict__ adjc,
    const unsigned short* __restrict__ Wt,
    const float* __restrict__ bias,
    const float* __restrict__ lnw, const float* __restrict__ lnb,
    const float* __restrict__ xres,
    void* __restrict__ outv)
{
    __shared__ __align__(16) char smem[3 * 8192];       // 24 KB: 3 A-tile buffers
    unsigned short* tile = (unsigned short*)smem;        // [3][64 rows][64] bf16
    float (*T)[68] = (float (*)[68])smem;                // epilogue reuse (17.4 KB)

    const int wave = threadIdx.x >> 6;
    const int lane = threadIdx.x & 63;
    const int l16 = lane & 15, lg = lane >> 4;
    const int nodeBase = blockIdx.x * 64;

    // Staging geometry: instr j (=2w, 2w+1) covers rows 8j..8j+7, 8 chunks of 16 B.
    const int srow = lane >> 3;              // row within group of 8 (== row&7)
    const int sswz = (lane & 7) ^ srow;      // pre-swizzled global chunk for this lane
    const int rA = wave * 16 + srow;
    const int rB = rA + 8;

    int idxA[NH], idxB[NH];
    {
        const int* a0 = adjc + (size_t)(nodeBase + rA) * NH;
        const int* a1 = adjc + (size_t)(nodeBase + rB) * NH;
#pragma unroll
        for (int hh = 0; hh < NH; ++hh) { idxA[hh] = a0[hh]; idxB[hh] = a1[hh]; }
    }

    // B fragments: lane holds o = 16*wave + l16, k = 32*s + lg*8 + [0..7]
    short8v bfrag[KSTEPS];
    {
        const unsigned short* wr = Wt + (size_t)(wave * 16 + l16) * K_TOT + lg * 8;
#pragma unroll
        for (int s = 0; s < KSTEPS; ++s) bfrag[s] = *(const short8v*)(wr + s * 32);
    }

    f32x4 acc[4];
#pragma unroll
    for (int m = 0; m < 4; ++m) acc[m] = (f32x4){0.f, 0.f, 0.f, 0.f};

#define STAGE(BUF, HH)                                                         \
    do {                                                                       \
        gload_lds16(h + (size_t)idxA[HH] * F + sswz * 8,                       \
                    (char*)tile + (BUF) * 8192 + (2 * wave) * 1024);           \
        gload_lds16(h + (size_t)idxB[HH] * F + sswz * 8,                       \
                    (char*)tile + (BUF) * 8192 + (2 * wave + 1) * 1024);       \
    } while (0)

#define COMPUTE(BUF, HH)                                                       \
    _Pragma("unroll")                                                          \
    for (int m = 0; m < 4; ++m) {                                              \
        _Pragma("unroll")                                                      \
        for (int kh = 0; kh < 2; ++kh) {                                       \
            const short8v a = *(const short8v*)((char*)tile + (BUF) * 8192     \
                + (m * 16 + l16) * 128 + (((kh * 4 + lg) ^ (l16 & 7)) * 16));  \
            acc[m] = __builtin_amdgcn_mfma_f32_16x16x32_bf16(                  \
                a, bfrag[(HH) * 2 + kh], acc[m], 0, 0, 0);                     \
        }                                                                      \
    }

    STAGE(0, 0);
    STAGE(1, 1);
#pragma unroll
    for (int hh = 0; hh < NH; ++hh) {
        if (hh < NH - 1) { asm volatile("s_waitcnt vmcnt(2)" ::: "memory"); }
        else             { asm volatile("s_waitcnt vmcnt(0)" ::: "memory"); }
        __builtin_amdgcn_s_barrier();
        if (hh < NH - 2) STAGE((hh + 2) % 3, hh + 2);   // issue early: 2 phases of cover
        COMPUTE(hh % 3, hh);
    }
#undef STAGE
#undef COMPUTE

    __syncthreads();   // all compute reads done before tile region is reused as T

    // Epilogue: transpose via LDS. D layout: row(node)=m*16+lg*4+r, col(o)=wave*16+l16
#pragma unroll
    for (int m = 0; m < 4; ++m)
#pragma unroll
        for (int r = 0; r < 4; ++r)
            T[m * 16 + lg * 4 + r][wave * 16 + l16] = acc[m][r];
    __syncthreads();

    const int t = threadIdx.x;
    const int nl = t >> 2, q = t & 3;                // 4 threads per node, 16 outputs each
    const int node = nodeBase + nl;
    float v[16];
#pragma unroll
    for (int i = 0; i < 16; ++i) v[i] = T[nl][q * 16 + i] + bias[q * 16 + i];

    if (FINAL) {
        float* out = (float*)outv;
#pragma unroll
        for (int i4 = 0; i4 < 4; ++i4) {
            const float4 xr = *(const float4*)(xres + (size_t)node * F + q * 16 + i4 * 4);
            float4 ov;
            ov.x = v[i4 * 4 + 0] + xr.x; ov.y = v[i4 * 4 + 1] + xr.y;
            ov.z = v[i4 * 4 + 2] + xr.z; ov.w = v[i4 * 4 + 3] + xr.w;
            *(float4*)(out + (size_t)node * F + q * 16 + i4 * 4) = ov;
        }
    } else {
        float s = 0.f, ss = 0.f;
#pragma unroll
        for (int i = 0; i < 16; ++i) { s += v[i]; ss += v[i] * v[i]; }
        s += __shfl_xor(s, 1); ss += __shfl_xor(ss, 1);
        s += __shfl_xor(s, 2); ss += __shfl_xor(ss, 2);
        const float mu = s * (1.0f / F);
        const float rstd = rsqrtf(ss * (1.0f / F) - mu * mu + LN_EPS);
        unsigned short* out = (unsigned short*)outv;
        unsigned short ob[16];
#pragma unroll
        for (int i = 0; i < 16; ++i) {
            const int o = q * 16 + i;
            const float y = (v[i] - mu) * rstd * lnw[o] + lnb[o];
            ob[i] = f2bf(silu_f(y));
        }
#pragma unroll
        for (int c = 0; c < 2; ++c)
            *(short8v*)(out + (size_t)node * F + q * 16 + c * 8) = *(short8v*)(ob + c * 8);
    }
}

extern "C" void kernel_launch(void* const* d_in, const int* in_sizes, int n_in,
                              void* d_out, int out_size, void* d_ws, size_t ws_size,
                              hipStream_t stream)
{
    const float* x    = (const float*)d_in[0];
    const int*   adjc = (const int*)d_in[1];
    const float* ln1w = (const float*)d_in[2];
    const float* ln1b = (const float*)d_in[3];
    const float* W1   = (const float*)d_in[4];
    const float* b1   = (const float*)d_in[5];
    const float* ln2w = (const float*)d_in[6];
    const float* ln2b = (const float*)d_in[7];
    const float* W2   = (const float*)d_in[8];
    const float* b2   = (const float*)d_in[9];
    float* out = (float*)d_out;

    unsigned short* h1  = (unsigned short*)d_ws;              // 25.2 MB bf16
    unsigned short* h2  = h1 + (size_t)NNODES * F;            // 25.2 MB bf16
    unsigned short* Wt1 = h2 + (size_t)NNODES * F;            // 144 KB
    unsigned short* Wt2 = Wt1 + F * K_TOT;                    // 144 KB

    prep_wt<<<(F * K_TOT + 255) / 256, 256, 0, stream>>>(W1, W2, Wt1, Wt2);
    ln1_silu<<<NNODES / 16, 256, 0, stream>>>(x, ln1w, ln1b, h1);
    gconv_mfma<0><<<NNODES / 64, 256, 0, stream>>>(h1, adjc, Wt1, b1, ln2w, ln2b, nullptr, h2);
    gconv_mfma<1><<<NNODES / 64, 256, 0, stream>>>(h2, adjc, Wt2, b2, nullptr, nullptr, x, out);
}

// Round 10
// 111.188 us; speedup vs baseline: 1.6332x; 1.1072x over previous
//
#include <hip/hip_runtime.h>

#define NNODES 196608
#define NH 9
#define F 64
#define K_TOT 576      // NH * F
#define KSTEPS 18      // K_TOT / 32
#define LN_EPS 1e-5f

typedef __attribute__((ext_vector_type(8))) short short8v;
typedef __attribute__((ext_vector_type(4))) float f32x4;

__device__ __forceinline__ unsigned short f2bf(float f) {
    unsigned int u = __float_as_uint(f);
    u += 0x7fff + ((u >> 16) & 1);          // round-to-nearest-even
    return (unsigned short)(u >> 16);
}
__device__ __forceinline__ float silu_f(float z) { return z / (1.0f + __expf(-z)); }

// Async global->LDS, 16 B per lane. Dest is wave-uniform base + lane*16 (linear).
__device__ __forceinline__ void gload_lds16(const void* g, void* l) {
    __builtin_amdgcn_global_load_lds((__attribute__((address_space(1))) void*)g,
                                     (__attribute__((address_space(3))) void*)l,
                                     16, 0, 0);
}

// Fragment-ordered bf16 weights (round-10): element (o,k) of B goes to
// Wt[((s*4 + w)*64 + lg*16 + l16)*8 + j], s=k/32, lg=(k%32)/8, j=k%8,
// w=o/16, l16=o%16 -> a wave's bfrag load is 64 lanes x 16B CONTIGUOUS (16 CLs
// vs 64 CLs for the old o-major layout: lane stride was 1152B).
__global__ __launch_bounds__(256) void prep_wt(const float* __restrict__ W1,
                                               const float* __restrict__ W2,
                                               unsigned short* __restrict__ Wt1,
                                               unsigned short* __restrict__ Wt2) {
    int tid = blockIdx.x * 256 + threadIdx.x;
    if (tid >= F * K_TOT) return;
    int o = tid & 63, k = tid >> 6;          // consecutive tid -> consecutive o (coalesced read)
    int s = k >> 5, lg = (k & 31) >> 3, j = k & 7;
    int w = o >> 4, l16 = o & 15;
    int dst = ((s * 4 + w) * 64 + lg * 16 + l16) * 8 + j;
    Wt1[dst] = f2bf(W1[(size_t)k * F + o]);
    Wt2[dst] = f2bf(W2[(size_t)k * F + o]);
}

// LN + SiLU, f32 in -> bf16 out. 16 threads per row, float4 per thread.
__global__ __launch_bounds__(256) void ln1_silu(const float* __restrict__ x,
                                                const float* __restrict__ w,
                                                const float* __restrict__ b,
                                                unsigned short* __restrict__ out) {
    const int t = threadIdx.x;
    const int row = blockIdx.x * 16 + (t >> 4);
    const int fl = (t & 15) * 4;
    const float4 v = *(const float4*)(x + (size_t)row * F + fl);
    float s = v.x + v.y + v.z + v.w;
    float ss = v.x * v.x + v.y * v.y + v.z * v.z + v.w * v.w;
#pragma unroll
    for (int o = 8; o; o >>= 1) { s += __shfl_xor(s, o); ss += __shfl_xor(ss, o); }
    const float mu = s * (1.0f / F);
    const float rstd = rsqrtf(ss * (1.0f / F) - mu * mu + LN_EPS);
    const float4 wv = *(const float4*)(w + fl);
    const float4 bv = *(const float4*)(b + fl);
    ushort4 o4;
    o4.x = f2bf(silu_f((v.x - mu) * rstd * wv.x + bv.x));
    o4.y = f2bf(silu_f((v.y - mu) * rstd * wv.y + bv.y));
    o4.z = f2bf(silu_f((v.z - mu) * rstd * wv.z + bv.z));
    o4.w = f2bf(silu_f((v.w - mu) * rstd * wv.w + bv.w));
    *(ushort4*)(out + (size_t)row * F + fl) = o4;
}

// Round-10: B off the in-loop VMEM path. bfrag[18] preloaded from the
// fragment-ordered Wt (coalesced) and PINNED resident via asm "+v" opacity
// (round 4/7/9: compiler remats register arrays back into the loop; an opaque
// asm-defined value cannot be remat'd). waves_per_eu(3,3) -> 168-VGPR cap fits.
// With zero in-loop B loads, the counted vmcnt tracks ONLY stage loads:
// depth-3 A prefetch (4 LDS buffers), steady-state vmcnt(4), tail 2/0.
// Round-9 transaction arithmetic: old o-major B loads = 64 CL/instr ~= 23us/CU
// of memory-pipe serialization + forced near-drain of the pipeline.
template<int FINAL>
__global__ __launch_bounds__(256) __attribute__((amdgpu_waves_per_eu(3, 3)))
void gconv_mfma(
    const unsigned short* __restrict__ h,
    const int* __restrict__ adjc,
    const unsigned short* __restrict__ Wt,
    const float* __restrict__ bias,
    const float* __restrict__ lnw, const float* __restrict__ lnb,
    const float* __restrict__ xres,
    void* __restrict__ outv)
{
    __shared__ __align__(16) char smem[4 * 8192];       // 32 KB: 4 A-tile buffers
    unsigned short* tile = (unsigned short*)smem;        // [4][64 rows][64] bf16
    float (*T)[68] = (float (*)[68])smem;                // epilogue reuse (17.4 KB)

    const int wave = threadIdx.x >> 6;
    const int lane = threadIdx.x & 63;
    const int l16 = lane & 15, lg = lane >> 4;
    const int nodeBase = blockIdx.x * 64;

    // Staging geometry: instr j (=2w, 2w+1) covers rows 8j..8j+7, 8 chunks of 16 B.
    const int srow = lane >> 3;              // row within group of 8 (== row&7)
    const int sswz = (lane & 7) ^ srow;      // pre-swizzled global chunk for this lane
    const int rA = wave * 16 + srow;
    const int rB = rA + 8;

    int idxA[NH], idxB[NH];
    {
        const int* a0 = adjc + (size_t)(nodeBase + rA) * NH;
        const int* a1 = adjc + (size_t)(nodeBase + rB) * NH;
#pragma unroll
        for (int hh = 0; hh < NH; ++hh) { idxA[hh] = a0[hh]; idxB[hh] = a1[hh]; }
    }

    // B fragments: coalesced preload (1 KB/wave/step), then pinned resident.
    short8v bfrag[KSTEPS];
    {
        const short8v* wp = (const short8v*)(Wt) + (size_t)wave * 64 + lane;
#pragma unroll
        for (int s = 0; s < KSTEPS; ++s) bfrag[s] = wp[(size_t)s * 256];
    }
#pragma unroll
    for (int s = 0; s < KSTEPS; ++s)
        asm volatile("" : "+v"(bfrag[s]));   // opaque: cannot be remat'd/sunk

    f32x4 acc[4];
#pragma unroll
    for (int m = 0; m < 4; ++m) acc[m] = (f32x4){0.f, 0.f, 0.f, 0.f};

#define STAGE(BUF, HH)                                                         \
    do {                                                                       \
        gload_lds16(h + (size_t)idxA[HH] * F + sswz * 8,                       \
                    (char*)tile + (BUF) * 8192 + (2 * wave) * 1024);           \
        gload_lds16(h + (size_t)idxB[HH] * F + sswz * 8,                       \
                    (char*)tile + (BUF) * 8192 + (2 * wave + 1) * 1024);       \
    } while (0)

#define COMPUTE(BUF, HH)                                                       \
    _Pragma("unroll")                                                          \
    for (int m = 0; m < 4; ++m) {                                              \
        _Pragma("unroll")                                                      \
        for (int kh = 0; kh < 2; ++kh) {                                       \
            const short8v a = *(const short8v*)((char*)tile + (BUF) * 8192     \
                + (m * 16 + l16) * 128 + (((kh * 4 + lg) ^ (l16 & 7)) * 16));  \
            acc[m] = __builtin_amdgcn_mfma_f32_16x16x32_bf16(                  \
                a, bfrag[(HH) * 2 + kh], acc[m], 0, 0, 0);                     \
        }                                                                      \
    }

    STAGE(0, 0);
    STAGE(1, 1);
    STAGE(2, 2);
#pragma unroll
    for (int hh = 0; hh < NH; ++hh) {
        if (hh <= NH - 3)      { asm volatile("s_waitcnt vmcnt(4)" ::: "memory"); }
        else if (hh == NH - 2) { asm volatile("s_waitcnt vmcnt(2)" ::: "memory"); }
        else                   { asm volatile("s_waitcnt vmcnt(0)" ::: "memory"); }
        __builtin_amdgcn_s_barrier();
        if (hh < NH - 3) STAGE((hh + 3) & 3, hh + 3);   // depth-3 prefetch
        COMPUTE(hh & 3, hh);
    }
#undef STAGE
#undef COMPUTE

    __syncthreads();   // all compute reads done before tile region is reused as T

    // Epilogue: transpose via LDS. D layout: row(node)=m*16+lg*4+r, col(o)=wave*16+l16
#pragma unroll
    for (int m = 0; m < 4; ++m)
#pragma unroll
        for (int r = 0; r < 4; ++r)
            T[m * 16 + lg * 4 + r][wave * 16 + l16] = acc[m][r];
    __syncthreads();

    const int t = threadIdx.x;
    const int nl = t >> 2, q = t & 3;                // 4 threads per node, 16 outputs each
    const int node = nodeBase + nl;
    float v[16];
#pragma unroll
    for (int i = 0; i < 16; ++i) v[i] = T[nl][q * 16 + i] + bias[q * 16 + i];

    if (FINAL) {
        float* out = (float*)outv;
#pragma unroll
        for (int i4 = 0; i4 < 4; ++i4) {
            const float4 xr = *(const float4*)(xres + (size_t)node * F + q * 16 + i4 * 4);
            float4 ov;
            ov.x = v[i4 * 4 + 0] + xr.x; ov.y = v[i4 * 4 + 1] + xr.y;
            ov.z = v[i4 * 4 + 2] + xr.z; ov.w = v[i4 * 4 + 3] + xr.w;
            *(float4*)(out + (size_t)node * F + q * 16 + i4 * 4) = ov;
        }
    } else {
        float s = 0.f, ss = 0.f;
#pragma unroll
        for (int i = 0; i < 16; ++i) { s += v[i]; ss += v[i] * v[i]; }
        s += __shfl_xor(s, 1); ss += __shfl_xor(ss, 1);
        s += __shfl_xor(s, 2); ss += __shfl_xor(ss, 2);
        const float mu = s * (1.0f / F);
        const float rstd = rsqrtf(ss * (1.0f / F) - mu * mu + LN_EPS);
        unsigned short* out = (unsigned short*)outv;
        unsigned short ob[16];
#pragma unroll
        for (int i = 0; i < 16; ++i) {
            const int o = q * 16 + i;
            const float y = (v[i] - mu) * rstd * lnw[o] + lnb[o];
            ob[i] = f2bf(silu_f(y));
        }
#pragma unroll
        for (int c = 0; c < 2; ++c)
            *(short8v*)(out + (size_t)node * F + q * 16 + c * 8) = *(short8v*)(ob + c * 8);
    }
}

extern "C" void kernel_launch(void* const* d_in, const int* in_sizes, int n_in,
                              void* d_out, int out_size, void* d_ws, size_t ws_size,
                              hipStream_t stream)
{
    const float* x    = (const float*)d_in[0];
    const int*   adjc = (const int*)d_in[1];
    const float* ln1w = (const float*)d_in[2];
    const float* ln1b = (const float*)d_in[3];
    const float* W1   = (const float*)d_in[4];
    const float* b1   = (const float*)d_in[5];
    const float* ln2w = (const float*)d_in[6];
    const float* ln2b = (const float*)d_in[7];
    const float* W2   = (const float*)d_in[8];
    const float* b2   = (const float*)d_in[9];
    float* out = (float*)d_out;

    unsigned short* h1  = (unsigned short*)d_ws;              // 25.2 MB bf16
    unsigned short* h2  = h1 + (size_t)NNODES * F;            // 25.2 MB bf16
    unsigned short* Wt1 = h2 + (size_t)NNODES * F;            // 144 KB
    unsigned short* Wt2 = Wt1 + F * K_TOT;                    // 144 KB

    prep_wt<<<(F * K_TOT + 255) / 256, 256, 0, stream>>>(W1, W2, Wt1, Wt2);
    ln1_silu<<<NNODES / 16, 256, 0, stream>>>(x, ln1w, ln1b, h1);
    gconv_mfma<0><<<NNODES / 64, 256, 0, stream>>>(h1, adjc, Wt1, b1, ln2w, ln2b, nullptr, h2);
    gconv_mfma<1><<<NNODES / 64, 256, 0, stream>>>(h2, adjc, Wt2, b2, nullptr, nullptr, x, out);
}